// Round 2
// 833.214 us; speedup vs baseline: 1.0079x; 1.0079x over previous
//
#include <hip/hip_runtime.h>
#include <cmath>

#define ENCD 128
#define DECD 128
#define INV_SQRT_D 0.08838834764831845f

// ---------------- init: zero the histogram counters ----------------
__global__ void init_counts(int* __restrict__ counts, int B) {
    int i = blockIdx.x * blockDim.x + threadIdx.x;
    if (i < B) counts[i] = 0;
}

// ---------------- qW = query[B,128] @ W[128,128] ----------------
__global__ void qw_gemm(const float* __restrict__ query, const float* __restrict__ W,
                        float* __restrict__ qW) {
    __shared__ float qs[8][DECD];
    const int t = threadIdx.x;
    const int row0 = blockIdx.x * 8;
    for (int i = t; i < 8 * DECD; i += 256)
        qs[i >> 7][i & 127] = query[(size_t)row0 * DECD + i];
    __syncthreads();
    const int c = t & 127;
    const int rh = t >> 7;  // 0..1
    float a0 = 0.f, a1 = 0.f, a2 = 0.f, a3 = 0.f;
    for (int k = 0; k < DECD; ++k) {
        const float w = W[k * ENCD + c];
        a0 += qs[rh * 4 + 0][k] * w;
        a1 += qs[rh * 4 + 1][k] * w;
        a2 += qs[rh * 4 + 2][k] * w;
        a3 += qs[rh * 4 + 3][k] * w;
    }
    qW[(size_t)(row0 + rh * 4 + 0) * ENCD + c] = a0;
    qW[(size_t)(row0 + rh * 4 + 1) * ENCD + c] = a1;
    qW[(size_t)(row0 + rh * 4 + 2) * ENCD + c] = a2;
    qW[(size_t)(row0 + rh * 4 + 3) * ENCD + c] = a3;
}

// ---------------- CSR build ----------------
__global__ void hist_kernel(const int* __restrict__ index, int* __restrict__ counts, int N) {
    int n4 = (blockIdx.x * blockDim.x + threadIdx.x) * 4;
    if (n4 + 3 < N) {
        const int4 v = *(const int4*)(index + n4);
        atomicAdd(&counts[v.x], 1);
        atomicAdd(&counts[v.y], 1);
        atomicAdd(&counts[v.z], 1);
        atomicAdd(&counts[v.w], 1);
    } else {
        for (int n = n4; n < N; ++n) atomicAdd(&counts[index[n]], 1);
    }
}

// single block, 1024 threads, scans up to 8192 counters (B=8192 here)
__global__ void scan_kernel(const int* __restrict__ counts, int* __restrict__ offsets,
                            int* __restrict__ cursor, int B) {
    __shared__ int tot[1024];
    const int t = threadIdx.x;
    int local[8];
    int s = 0;
#pragma unroll
    for (int i = 0; i < 8; ++i) {
        const int ci = t * 8 + i;
        local[i] = (ci < B) ? counts[ci] : 0;
        s += local[i];
    }
    tot[t] = s;
    __syncthreads();
    for (int off = 1; off < 1024; off <<= 1) {
        int v = (t >= off) ? tot[t - off] : 0;
        __syncthreads();
        tot[t] += v;
        __syncthreads();
    }
    int excl = tot[t] - s;
#pragma unroll
    for (int i = 0; i < 8; ++i) {
        const int ci = t * 8 + i;
        if (ci < B) { offsets[ci] = excl; cursor[ci] = excl; }
        excl += local[i];
    }
    if (t == 1023) offsets[B] = tot[1023];
}

__global__ void scatter_kernel(const int* __restrict__ index, int* __restrict__ cursor,
                               int* __restrict__ nodeids, int N) {
    int n4 = (blockIdx.x * blockDim.x + threadIdx.x) * 4;
    if (n4 + 3 < N) {
        const int4 v = *(const int4*)(index + n4);
        const int p0 = atomicAdd(&cursor[v.x], 1); nodeids[p0] = n4 + 0;
        const int p1 = atomicAdd(&cursor[v.y], 1); nodeids[p1] = n4 + 1;
        const int p2 = atomicAdd(&cursor[v.z], 1); nodeids[p2] = n4 + 2;
        const int p3 = atomicAdd(&cursor[v.w], 1); nodeids[p3] = n4 + 3;
    } else {
        for (int n = n4; n < N; ++n) {
            const int p = atomicAdd(&cursor[index[n]], 1);
            nodeids[p] = n;
        }
    }
}

// ---------------- main: wave-autonomous per-segment online-softmax pooling ----------------
// One block (4 waves) per segment. Each wave independently processes 8 rows per
// iteration (positions beg + w*8 + 32*it + (lane&7)), keeps its own 128-column
// accumulator (2 cols/lane) plus a per-wave running max (online softmax), and
// merges once at the end. ZERO __syncthreads in the main loop: row data is
// staged into a wave-private LDS region (same-wave DS ops are in-order), and
// next-iteration rows + nodeids are register-prefetched so scattered HBM
// latency hides under compute without barriers.
//
// Online max is cheap in this layout: after the g-butterfly, lanes sharing a
// row slot all hold that row's full dot, so a 3-step shfl_xor max over bits
// 0..2 gives the 8-row chunk max to every lane; m is wave-uniform and the
// rescale is 3 FMAs per 8 rows. (R1 post-mortem: the unstable-softmax clamp
// at 60 bound in segments where (sum q)^2 inflates ||qW|| — scores reach 55-70
// because W~U(0,1) has mean 0.5. Online max handles any distribution.)
__device__ __forceinline__ float dot4(const float4 a, const float4 b) {
    return a.x * b.x + a.y * b.y + a.z * b.z + a.w * b.w;
}

#define SEG_ITER(CUR, NXT, P)                                                  \
  {                                                                            \
    float pd = dot4(CUR[0], q4[0]) + dot4(CUR[1], q4[1]) +                     \
               dot4(CUR[2], q4[2]) + dot4(CUR[3], q4[3]);                      \
    pd += __shfl_xor(pd, 8);                                                   \
    pd += __shfl_xor(pd, 16);                                                  \
    pd += __shfl_xor(pd, 32);                                                  \
    const float sc = ((P) + r < end) ? pd * INV_SQRT_D : -INFINITY;            \
    float mc = sc;                                                             \
    mc = fmaxf(mc, __shfl_xor(mc, 1));                                         \
    mc = fmaxf(mc, __shfl_xor(mc, 2));                                         \
    mc = fmaxf(mc, __shfl_xor(mc, 4));                                         \
    const float m_new = fmaxf(m, mc);      /* finite: row (P)+0 always valid */\
    const float scale = __expf(m - m_new); /* first iter: exp(-inf)=0 */       \
    const float pe = __expf(sc - m_new);   /* invalid rows: exp(-inf)=0 */     \
    float* dst = &vsh[w][r][g * 16];                                           \
    *(float4*)(dst + 0)  = CUR[0];                                             \
    *(float4*)(dst + 4)  = CUR[1];                                             \
    *(float4*)(dst + 8)  = CUR[2];                                             \
    *(float4*)(dst + 12) = CUR[3];                                             \
    if ((P) + 32 < end) {  /* wave-uniform guard */                            \
      const float* vp = values + (size_t)nid_next * ENCD + g * 16;             \
      NXT[0] = *(const float4*)(vp + 0);                                       \
      NXT[1] = *(const float4*)(vp + 4);                                       \
      NXT[2] = *(const float4*)(vp + 8);                                       \
      NXT[3] = *(const float4*)(vp + 12);                                      \
      const int nn = (P) + 64 + r;                                             \
      nid_next = nodeids[(nn < end) ? nn : beg];                               \
    }                                                                          \
    float psum = 0.f, ad0 = 0.f, ad1 = 0.f;                                    \
    _Pragma("unroll")                                                          \
    for (int j = 0; j < 8; ++j) {                                              \
      const float pj = __shfl(pe, j);  /* row j's weight, broadcast */         \
      psum += pj;                                                              \
      ad0 += pj * vsh[w][j][l];        /* stride-1 across lanes: 2-way, free */\
      ad1 += pj * vsh[w][j][l + 64];                                           \
    }                                                                          \
    acc0 = acc0 * scale + ad0;                                                 \
    acc1 = acc1 * scale + ad1;                                                 \
    lacc = lacc * scale + psum;                                                \
    m = m_new;                                                                 \
  }

__global__ __launch_bounds__(256) void seg_attn(
    const float* __restrict__ values, const float* __restrict__ qW,
    const int* __restrict__ offsets, const int* __restrict__ nodeids,
    float* __restrict__ out) {
    const int b = blockIdx.x;
    const int t = threadIdx.x;
    const int w = t >> 6;   // wave 0..3
    const int l = t & 63;   // lane
    const int r = l & 7;    // row slot 0..7 (8 lanes per row)
    const int g = l >> 3;   // col group 0..7 (16 floats each)

    const int beg = offsets[b];
    const int end = offsets[b + 1];

    __shared__ float vsh[4][8][ENCD + 4];  // wave-private staging, +4 pad
    __shared__ float mrg_a[4][ENCD];
    __shared__ float mrg_l[4];
    __shared__ float mrg_m[4];

    // q fragment for this lane's col group (same for all 8 row-slot lanes)
    float4 q4[4];
#pragma unroll
    for (int i = 0; i < 4; ++i)
        q4[i] = *(const float4*)(qW + (size_t)b * ENCD + g * 16 + i * 4);

    float acc0 = 0.f, acc1 = 0.f, lacc = 0.f;
    float m = -INFINITY;
    float4 va[4], vb[4];
    int nid_next = 0;

    int p = beg + w * 8;
    if (p < end) {
        // prologue: load rows for iter 0 and nodeids for iter 1
        {
            const int pp = p + r;
            const int nid0 = nodeids[(pp < end) ? pp : beg];
            const float* vp = values + (size_t)nid0 * ENCD + g * 16;
            va[0] = *(const float4*)(vp + 0);
            va[1] = *(const float4*)(vp + 4);
            va[2] = *(const float4*)(vp + 8);
            va[3] = *(const float4*)(vp + 12);
            const int np = p + 32 + r;
            nid_next = nodeids[(np < end) ? np : beg];
        }
        while (true) {
            SEG_ITER(va, vb, p);
            p += 32;
            if (p >= end) break;
            SEG_ITER(vb, va, p);
            p += 32;
            if (p >= end) break;
        }
    }

    // merge the 4 per-wave partials (rescale each to the cross-wave max)
    mrg_a[w][l] = acc0;
    mrg_a[w][l + 64] = acc1;
    if (l == 0) { mrg_l[w] = lacc; mrg_m[w] = m; }
    __syncthreads();
    if (t < ENCD) {
        const float mt = fmaxf(fmaxf(mrg_m[0], mrg_m[1]), fmaxf(mrg_m[2], mrg_m[3]));
        float a = 0.f, lt = 0.f;
#pragma unroll
        for (int ww = 0; ww < 4; ++ww) {
            const float mw = mrg_m[ww];
            // mw==mt guard: empty segments (both -inf) give rs=1 on zero
            // accumulators instead of exp(nan); skipped waves give rs=0.
            const float rs = (mw == mt) ? 1.f : __expf(mw - mt);
            a += rs * mrg_a[ww][t];
            lt += rs * mrg_l[ww];
        }
        out[(size_t)b * ENCD + t] = (lt > 0.f) ? (a / lt) : 0.f;
    }
}

extern "C" void kernel_launch(void* const* d_in, const int* in_sizes, int n_in,
                              void* d_out, int out_size, void* d_ws, size_t ws_size,
                              hipStream_t stream) {
    const float* query  = (const float*)d_in[0];   // [B,128]
    const float* values = (const float*)d_in[1];   // [N,128]
    const int*   index  = (const int*)d_in[2];     // [N]
    const float* W      = (const float*)d_in[3];   // [128,128]
    float* out = (float*)d_out;                    // [B,128]

    const int B = in_sizes[0] / DECD;   // 8192
    const int N = in_sizes[2];          // 1,000,000

    // workspace carve (~8.3 MB)
    float* qW      = (float*)d_ws;                    // B*128 floats
    int*   nodeids = (int*)(qW + (size_t)B * ENCD);   // N ints
    int*   counts  = nodeids + N;                     // B
    int*   offsets = counts + B;                      // B+1
    int*   cursor  = offsets + B + 1;                 // B

    init_counts<<<(B + 255) / 256, 256, 0, stream>>>(counts, B);
    qw_gemm<<<B / 8, 256, 0, stream>>>(query, W, qW);
    hist_kernel<<<(N / 4 + 255) / 256, 256, 0, stream>>>(index, counts, N);
    scan_kernel<<<1, 1024, 0, stream>>>(counts, offsets, cursor, B);
    scatter_kernel<<<(N / 4 + 255) / 256, 256, 0, stream>>>(index, cursor, nodeids, N);
    seg_attn<<<B, 256, 0, stream>>>(values, qW, offsets, nodeids, out);
}